// Round 1
// baseline (311.925 us; speedup 1.0000x reference)
//
#include <hip/hip_runtime.h>
#include <math.h>

// Problem constants (B=2, S=1024, H=12, HS=64, ALL=768, P=128)
#define SEQ   1024
#define BATCH 2
#define NH    12
#define HS_   64
#define ALLD  768
#define ALL2  1536
// 1/scaling = 1/64^0.25
#define INVS  0.35355339059327373f

// ---------------------------------------------------------------------------
// K1: u = p1 @ W_qk + b_qk ; q = u[:, :768]*INVS ; k = u[:, 768:]*INVS
// M = B*S = 2048, N = 1536, K = 768. 64x64 tile, 256 thr, 4x4 per thread.
// ---------------------------------------------------------------------------
__global__ __launch_bounds__(256) void qk_gemm(
    const float* __restrict__ p1, const float* __restrict__ Wqk,
    const float* __restrict__ bqk, float* __restrict__ qo,
    float* __restrict__ ko) {
  const int tid = threadIdx.x;
  const int tx = tid & 15, ty = tid >> 4;
  const int m0 = blockIdx.x * 64;
  const int n0 = blockIdx.y * 64;

  __shared__ float As[16][64];  // [k][m]
  __shared__ float Bs[16][64];  // [k][n]

  float acc[4][4];
#pragma unroll
  for (int i = 0; i < 4; ++i)
#pragma unroll
    for (int j = 0; j < 4; ++j) acc[i][j] = 0.f;

  const int lm = tid >> 2;         // 0..63 A row
  const int lk = (tid & 3) * 4;    // 0,4,8,12
  const int bk = tid >> 4;         // 0..15 B row
  const int bn = (tid & 15) * 4;   // 0..60

  for (int kk = 0; kk < 768; kk += 16) {
    float4 av = *(const float4*)(p1 + (size_t)(m0 + lm) * 768 + kk + lk);
    float4 bv = *(const float4*)(Wqk + (size_t)(kk + bk) * 1536 + n0 + bn);
    __syncthreads();
    As[lk + 0][lm] = av.x;
    As[lk + 1][lm] = av.y;
    As[lk + 2][lm] = av.z;
    As[lk + 3][lm] = av.w;
    *(float4*)&Bs[bk][bn] = bv;
    __syncthreads();
#pragma unroll
    for (int kq = 0; kq < 16; ++kq) {
      float4 a = *(const float4*)&As[kq][ty * 4];
      float4 b = *(const float4*)&Bs[kq][tx * 4];
      acc[0][0] += a.x * b.x; acc[0][1] += a.x * b.y;
      acc[0][2] += a.x * b.z; acc[0][3] += a.x * b.w;
      acc[1][0] += a.y * b.x; acc[1][1] += a.y * b.y;
      acc[1][2] += a.y * b.z; acc[1][3] += a.y * b.w;
      acc[2][0] += a.z * b.x; acc[2][1] += a.z * b.y;
      acc[2][2] += a.z * b.z; acc[2][3] += a.z * b.w;
      acc[3][0] += a.w * b.x; acc[3][1] += a.w * b.y;
      acc[3][2] += a.w * b.z; acc[3][3] += a.w * b.w;
    }
  }

#pragma unroll
  for (int i = 0; i < 4; ++i) {
    const int m = m0 + ty * 4 + i;
#pragma unroll
    for (int j = 0; j < 4; ++j) {
      const int n = n0 + tx * 4 + j;
      float v = (acc[i][j] + bqk[n]) * INVS;
      if (n < ALLD)
        qo[(size_t)m * ALLD + n] = v;
      else
        ko[(size_t)m * ALLD + (n - ALLD)] = v;
    }
  }
}

// ---------------------------------------------------------------------------
// K2: QR[b,s,id,h] = sum_d q[b,s,h*64+d] * rel_emb[id,d] * INVS
// One block per (b*S + s); thread = id (256 ids).
// ---------------------------------------------------------------------------
__global__ __launch_bounds__(256) void qr_kernel(
    const float* __restrict__ q, const float* __restrict__ rel,
    float* __restrict__ QR) {
  const int bs = blockIdx.x;  // 0..2047
  const int tid = threadIdx.x;

  __shared__ float qs[768];
  qs[tid] = q[(size_t)bs * 768 + tid];
  qs[tid + 256] = q[(size_t)bs * 768 + tid + 256];
  qs[tid + 512] = q[(size_t)bs * 768 + tid + 512];
  __syncthreads();

  const float* rrow = rel + (size_t)tid * 64;
  float o[12];
#pragma unroll
  for (int h = 0; h < 12; ++h) o[h] = 0.f;

#pragma unroll
  for (int d4 = 0; d4 < 64; d4 += 4) {
    float4 rv = *(const float4*)(rrow + d4);
#pragma unroll
    for (int h = 0; h < 12; ++h) {
      o[h] += qs[h * 64 + d4 + 0] * rv.x + qs[h * 64 + d4 + 1] * rv.y +
              qs[h * 64 + d4 + 2] * rv.z + qs[h * 64 + d4 + 3] * rv.w;
    }
  }

  float* dst = QR + ((size_t)bs * 256 + tid) * 12;
#pragma unroll
  for (int h = 0; h < 12; h += 4) {
    float4 v;
    v.x = o[h + 0] * INVS;
    v.y = o[h + 1] * INVS;
    v.z = o[h + 2] * INVS;
    v.w = o[h + 3] * INVS;
    *(float4*)(dst + h) = v;
  }
}

// ---------------------------------------------------------------------------
// K3: fused scores + bias + writer.
// Tile: 64 s x 32 t per block, 256 threads, each thread 4 s x 2 t pairs.
// Phase 1: per-head scores via transposed LDS tiles.
// Phase 1.5: add QR bias (48B contiguous gathers).
// Phase 2: chunked LDS transpose + writer (sum over h) + coalesced stores.
// ---------------------------------------------------------------------------
__global__ __launch_bounds__(256) void main_kernel(
    const float* __restrict__ q, const float* __restrict__ k,
    const float* __restrict__ QR, const float* __restrict__ Wout,
    const float* __restrict__ bout, float* __restrict__ out) {
  const int tid = threadIdx.x;
  const int tx = tid & 15, ty = tid >> 4;
  const int b = blockIdx.z;
  const int s0 = blockIdx.y * 64;
  const int t0 = blockIdx.x * 32;

  __shared__ float smem[64 * 68 + 64 * 34];  // 26112 B
  __shared__ float Wl[768];
  __shared__ float bol[64];
  float(*qs)[68] = (float(*)[68])smem;              // [d][s]
  float(*ks)[34] = (float(*)[34])(smem + 64 * 68);  // [d][t]
  float(*scs)[12] = (float(*)[12])smem;             // writer: [p][h], 512x12

  Wl[tid] = Wout[tid];
  Wl[tid + 256] = Wout[tid + 256];
  Wl[tid + 512] = Wout[tid + 512];
  if (tid < 64) bol[tid] = bout[tid];

  float sc[12][4][2];
#pragma unroll
  for (int h = 0; h < 12; ++h)
#pragma unroll
    for (int i = 0; i < 4; ++i)
#pragma unroll
      for (int j = 0; j < 2; ++j) sc[h][i][j] = 0.f;

  const float* qbase = q + ((size_t)b * SEQ + s0) * 768;
  const float* kbase = k + ((size_t)b * SEQ + t0) * 768;

#pragma unroll
  for (int h = 0; h < 12; ++h) {
    __syncthreads();
    // stage q tile transposed: qs[d][si], 64x64
#pragma unroll
    for (int r = 0; r < 4; ++r) {
      int f = tid + 256 * r;
      int si = f >> 4;           // 0..63
      int d4 = (f & 15) * 4;     // 0..60
      float4 v = *(const float4*)(qbase + (size_t)si * 768 + h * 64 + d4);
      qs[d4 + 0][si] = v.x;
      qs[d4 + 1][si] = v.y;
      qs[d4 + 2][si] = v.z;
      qs[d4 + 3][si] = v.w;
    }
    // stage k tile transposed: ks[d][tj], 64x32
#pragma unroll
    for (int r = 0; r < 2; ++r) {
      int f = tid + 256 * r;
      int tj = f >> 4;           // 0..31
      int d4 = (f & 15) * 4;
      float4 v = *(const float4*)(kbase + (size_t)tj * 768 + h * 64 + d4);
      ks[d4 + 0][tj] = v.x;
      ks[d4 + 1][tj] = v.y;
      ks[d4 + 2][tj] = v.z;
      ks[d4 + 3][tj] = v.w;
    }
    __syncthreads();
#pragma unroll 8
    for (int d = 0; d < 64; ++d) {
      float4 qa = *(const float4*)&qs[d][ty * 4];
      float2 kb = *(const float2*)&ks[d][tx * 2];
      sc[h][0][0] += qa.x * kb.x; sc[h][0][1] += qa.x * kb.y;
      sc[h][1][0] += qa.y * kb.x; sc[h][1][1] += qa.y * kb.y;
      sc[h][2][0] += qa.z * kb.x; sc[h][2][1] += qa.z * kb.y;
      sc[h][3][0] += qa.w * kb.x; sc[h][3][1] += qa.w * kb.y;
    }
  }

  // bias from QR
#pragma unroll
  for (int i = 0; i < 4; ++i) {
#pragma unroll
    for (int j = 0; j < 2; ++j) {
      const int s = s0 + ty * 4 + i;
      const int t = t0 + tx * 2 + j;
      const int d = t - s;
      const int id = (d >= 0) ? (d < 127 ? d : 127)
                              : (256 + (d > -127 ? d : -127));
      const float* qr = QR + ((size_t)(b * SEQ + s) * 256 + id) * 12;
      float4 r0 = *(const float4*)(qr + 0);
      float4 r1 = *(const float4*)(qr + 4);
      float4 r2 = *(const float4*)(qr + 8);
      sc[0][i][j] += r0.x;  sc[1][i][j] += r0.y;
      sc[2][i][j] += r0.z;  sc[3][i][j] += r0.w;
      sc[4][i][j] += r1.x;  sc[5][i][j] += r1.y;
      sc[6][i][j] += r1.z;  sc[7][i][j] += r1.w;
      sc[8][i][j] += r2.x;  sc[9][i][j] += r2.y;
      sc[10][i][j] += r2.z; sc[11][i][j] += r2.w;
    }
  }

  // writer: 4 chunks of 16 s-rows (512 pairs each)
  const int c4 = tid & 15;
  const int pb = tid >> 4;
#pragma unroll 1
  for (int ch = 0; ch < 4; ++ch) {
    __syncthreads();
    if ((ty >> 2) == ch) {
      const int tyl = ty & 3;
#pragma unroll
      for (int i = 0; i < 4; ++i)
#pragma unroll
        for (int j = 0; j < 2; ++j) {
          const int p = (tyl * 4 + i) * 32 + tx * 2 + j;
#pragma unroll
          for (int h = 0; h < 12; ++h) scs[p][h] = sc[h][i][j];
        }
    }
    __syncthreads();
    float* obase = out + (((size_t)b * SEQ + s0 + ch * 16) * SEQ + t0) * 64;
#pragma unroll 1
    for (int pp = 0; pp < 32; ++pp) {
      const int p = pp * 16 + pb;
      float sv[12];
#pragma unroll
      for (int h = 0; h < 12; ++h) sv[h] = scs[p][h];
      float4 o = *(const float4*)&bol[c4 * 4];
#pragma unroll
      for (int h = 0; h < 12; ++h) {
        float4 w = *(const float4*)&Wl[h * 64 + c4 * 4];
        o.x += sv[h] * w.x;
        o.y += sv[h] * w.y;
        o.z += sv[h] * w.z;
        o.w += sv[h] * w.w;
      }
      const int sl = p >> 5;
      const int tl = p & 31;
      *(float4*)(obase + ((size_t)sl * SEQ + tl) * 64 + c4 * 4) = o;
    }
  }
}

// ---------------------------------------------------------------------------
extern "C" void kernel_launch(void* const* d_in, const int* in_sizes, int n_in,
                              void* d_out, int out_size, void* d_ws,
                              size_t ws_size, hipStream_t stream) {
  const float* p1 = (const float*)d_in[1];
  const float* Wqk = (const float*)d_in[3];
  const float* bqk = (const float*)d_in[4];
  const float* rel = (const float*)d_in[5];
  const float* Wout = (const float*)d_in[6];
  const float* bout = (const float*)d_in[7];
  float* out = (float*)d_out;

  // workspace layout (fp32): q[2*1024*768] | k[2*1024*768] | QR[2*1024*256*12]
  float* qo = (float*)d_ws;
  float* ko = qo + (size_t)BATCH * SEQ * ALLD;
  float* QR = ko + (size_t)BATCH * SEQ * ALLD;
  // total: 2*6.29MB + 25.2MB = 37.8 MB of ws

  hipLaunchKernelGGL(qk_gemm, dim3(32, 24), dim3(256), 0, stream, p1, Wqk, bqk,
                     qo, ko);
  hipLaunchKernelGGL(qr_kernel, dim3(BATCH * SEQ), dim3(256), 0, stream, qo,
                     rel, QR);
  hipLaunchKernelGGL(main_kernel, dim3(SEQ / 32, SEQ / 64, BATCH), dim3(256), 0,
                     stream, qo, ko, QR, Wout, bout, out);
}